// Round 1
// baseline (169.911 us; speedup 1.0000x reference)
//
#include <hip/hip_runtime.h>

#define Mdim 8
#define Tdim 4000
#define Bdim 128
#define Hdim 512
#define NPER (Tdim*Hdim)
#define EPSG 1e-8f
#define ROWS 69   // 64-t tile + 5 halo rows (t0-2 .. t0+66)

typedef __attribute__((ext_vector_type(8))) short short8;
typedef __attribute__((ext_vector_type(4))) float floatx4;

static __device__ __forceinline__ float bits2f(unsigned short s) {
  union { unsigned int u; float f; } v; v.u = ((unsigned int)s) << 16; return v.f;
}
static __device__ __forceinline__ unsigned short f2bits(float f) {
  union { float f; unsigned int u; } v; v.f = f;
  unsigned int u = v.u;
  u += 0x7fffu + ((u >> 16) & 1u);   // RNE
  return (unsigned short)(u >> 16);
}
static __device__ __forceinline__ short8 pack8(const float4& a, const float4& b) {
  short8 v;
  v[0]=(short)f2bits(a.x); v[1]=(short)f2bits(a.y); v[2]=(short)f2bits(a.z); v[3]=(short)f2bits(a.w);
  v[4]=(short)f2bits(b.x); v[5]=(short)f2bits(b.y); v[6]=(short)f2bits(b.z); v[7]=(short)f2bits(b.w);
  return v;
}

// wave-local LDS fence: all lanes' ds ops drained; lockstep => covers cross-lane within wave
#define LDS_FENCE() do { \
  asm volatile("s_waitcnt lgkmcnt(0)" ::: "memory"); \
  __builtin_amdgcn_sched_barrier(0); \
} while (0)

// ---------------- K0: convert w1 [512,128] f32 -> fragment-ordered bf16 (once, not per block)
// layout: short8 index i = (hc*16 + ks*4 + nt)*64 + lane; h = hc*64+nt*16+(lane&15), c = ks*32+(lane>>4)*8
__global__ __launch_bounds__(256) void k_prep(
    const float* __restrict__ w1, unsigned short* __restrict__ w1r)
{
  int i = blockIdx.x*256 + threadIdx.x;    // 8192 short8 fragments
  int lane = i & 63, f = i >> 6;
  int nt = f & 3, ks = (f >> 2) & 3, hc = f >> 4;
  int h = hc*64 + nt*16 + (lane & 15);
  int c = ks*32 + (lane >> 4)*8;
  const float* src = &w1[(size_t)h*Bdim + c];
  float4 a = *(const float4*)src;
  float4 b = *(const float4*)(src + 4);
  *(short8*)&w1r[(size_t)i*8] = pack8(a, b);
}

// ---------------- K1: conv1 GEMM + PReLU + gLN1 partials -> Hbuf [M,T,H] bf16
// merged h-halves (x packed once); B-fragments direct from global (L2-resident w1r); no block barriers.
__global__ __launch_bounds__(256) void k_conv1(
    const float* __restrict__ x,
    const unsigned short* __restrict__ w1r,
    const float* __restrict__ a1p,
    unsigned short* __restrict__ Hbuf,
    float2* __restrict__ part1)
{
  __shared__ __align__(16) unsigned short ltile[64*72];
  __shared__ float red[512];

  const int tid = threadIdx.x;
  const int t0 = blockIdx.x * 64;
  const int m  = blockIdx.y;
  const int lane = tid & 63, wv = tid >> 6, quad = lane >> 4, l16 = lane & 15;
  int tr = t0 + wv*16 + l16;
  int trc = tr < Tdim ? tr : Tdim-1;
  const float* xrow = x + ((size_t)m*Tdim + trc)*Bdim;
  short8 afr[4];
  #pragma unroll
  for (int ks = 0; ks < 4; ++ks) {
    float4 fa = *(const float4*)&xrow[ks*32 + quad*8];
    float4 fb = *(const float4*)&xrow[ks*32 + quad*8 + 4];
    afr[ks] = pack8(fa, fb);
  }

  const float a1 = a1p[0];
  const short8* wf = (const short8*)w1r + lane;
  float lsum = 0.f, lss = 0.f;

  for (int hc = 0; hc < 8; ++hc) {
    floatx4 acc[4] = {};
    #pragma unroll
    for (int ks = 0; ks < 4; ++ks)
      #pragma unroll
      for (int nt = 0; nt < 4; ++nt)
        acc[nt] = __builtin_amdgcn_mfma_f32_16x16x32_bf16(
            afr[ks], wf[(hc*16 + ks*4 + nt)*64], acc[nt], 0, 0, 0);

    #pragma unroll
    for (int nt = 0; nt < 4; ++nt) {
      int hl = nt*16 + l16;                 // C/D: col = lane&15
      #pragma unroll
      for (int r = 0; r < 4; ++r) {
        int tl = wv*16 + quad*4 + r;        // C/D: row = quad*4+reg
        float v = acc[nt][r];
        v = v >= 0.f ? v : a1 * v;
        if (t0 + tl < Tdim) { lsum += v; lss += v*v; }
        ltile[tl*72 + hl] = f2bits(v);
      }
    }
    LDS_FENCE();   // writes visible to same-wave cross-lane reads
    {
      int tr2 = tid >> 2, ck = (tid & 3) * 16;
      int tg = t0 + tr2;
      if (tg < Tdim) {
        unsigned short* dst = &Hbuf[((size_t)m*Tdim + tg)*Hdim + hc*64 + ck];
        *(short8*)&dst[0] = *(const short8*)&ltile[tr2*72 + ck];
        *(short8*)&dst[8] = *(const short8*)&ltile[tr2*72 + ck + 8];
      }
    }
    LDS_FENCE();   // reads drained before next iteration overwrites
  }

  red[tid] = lsum; red[256 + tid] = lss;
  __syncthreads();
  for (int s = 128; s > 0; s >>= 1) {
    if (tid < s) { red[tid] += red[tid + s]; red[256+tid] += red[256+tid+s]; }
    __syncthreads();
  }
  if (tid == 0)
    part1[(size_t)m*63 + blockIdx.x] = make_float2(red[0], red[256]);
}

// ---------------- K2: fused offsets + deformable dw conv + PReLU2 + gLN2 partials -> Ybuf
// 64-t block tile; 69-row Hbuf band staged once in LDS (reflect folded into staging);
// all offset/gather reads are LDS (conflict-free whole-row reads).
__global__ __launch_bounds__(256) void k_deform(
    const unsigned short* __restrict__ Hbuf,
    const float2* __restrict__ part1,
    const float* __restrict__ g1w,
    const float* __restrict__ b1w,
    const float* __restrict__ odw,
    const float* __restrict__ aodcp,
    const float* __restrict__ opw,
    const float* __restrict__ aopcp,
    const float* __restrict__ dww,
    const float* __restrict__ dwb,
    const float* __restrict__ a2p,
    unsigned short* __restrict__ Ybuf,
    float2* __restrict__ part2)
{
  __shared__ __align__(16) unsigned short tile[ROWS*512];   // 70656 B -> 2 blocks/CU
  __shared__ float s_stats[2];
  __shared__ float rsum[4], rss[4];
  const int tid = threadIdx.x, lane = tid & 63, w = tid >> 6;
  const int t0 = blockIdx.x * 64;
  const int m = blockIdx.y;
  const int c8 = lane*8;
  const unsigned short* base = Hbuf + (size_t)m*Tdim*Hdim;

  // ---- stage rows t0-2 .. t0+66 (reflected) : issue all loads early, write late ----
  short8 stg[17];
  #pragma unroll
  for (int i = 0; i < 17; ++i) {
    int s = t0 - 2 + w + i*4;
    s = s < 0 ? -s : s;
    if (s > Tdim-1) s = 2*(Tdim-1) - s;
    stg[i] = *(const short8*)&base[(size_t)s*Hdim + c8];
  }
  short8 extra;
  if (w == 0) {
    int s = t0 + 66;
    if (s > Tdim-1) s = 2*(Tdim-1) - s;
    extra = *(const short8*)&base[(size_t)s*Hdim + c8];
  }

  // stats reduce of part1 (63 entries) while staging loads are in flight
  if (tid < 64) {
    float s = 0.f, q = 0.f;
    if (lane < 63) { float2 p = part1[(size_t)m*63 + lane]; s = p.x; q = p.y; }
    #pragma unroll
    for (int st = 32; st > 0; st >>= 1) { s += __shfl_xor(s, st); q += __shfl_xor(q, st); }
    if (lane == 0) { s_stats[0] = s; s_stats[1] = q; }
  }

  #pragma unroll
  for (int i = 0; i < 17; ++i)
    *(short8*)&tile[(w + i*4)*512 + c8] = stg[i];
  if (w == 0) *(short8*)&tile[68*512 + c8] = extra;

  __syncthreads();

  const float invn = 1.0f/(float)NPER;
  const float mean1 = s_stats[0]*invn;
  const float var1  = fmaxf(s_stats[1]*invn - mean1*mean1, 0.f);
  const float inv1  = 1.0f/sqrtf(var1 + EPSG);

  const float aodc = aodcp[0], aopc = aopcp[0], a2 = a2p[0];
  float wod[24], q0v[8], q1v[8], q2v[8], wd[24], bv[8], Ax[8], Cx[8];
  #pragma unroll
  for (int j = 0; j < 8; j += 4) {
    *(float4*)&q0v[j] = *(const float4*)&opw[c8 + j];
    *(float4*)&q1v[j] = *(const float4*)&opw[Hdim + c8 + j];
    *(float4*)&q2v[j] = *(const float4*)&opw[2*Hdim + c8 + j];
    *(float4*)&bv[j]  = *(const float4*)&dwb[c8 + j];
  }
  #pragma unroll
  for (int j = 0; j < 24; j += 4) {
    *(float4*)&wod[j] = *(const float4*)&odw[c8*3 + j];
    *(float4*)&wd[j]  = *(const float4*)&dww[c8*3 + j];
  }
  #pragma unroll
  for (int j = 0; j < 8; ++j) {
    Ax[j] = g1w[c8 + j] * inv1;
    Cx[j] = b1w[c8 + j] - mean1*Ax[j];
  }

  float lsum = 0.f, lss = 0.f;
  #pragma unroll 1
  for (int it = 0; it < 16; it += 2) {
    const int t = t0 + w*16 + it;          // wave-uniform
    if (t >= Tdim) break;                  // Tdim even -> pairs never split
    const int sb = t - t0 + 2;             // LDS slot of row t

    short8 hrow[2][3];
    #pragma unroll
    for (int tt = 0; tt < 2; ++tt)
      #pragma unroll
      for (int k = 0; k < 3; ++k)
        hrow[tt][k] = *(const short8*)&tile[(sb + tt - 1 + k)*512 + c8];

    // ---- offset branch (both t) ----
    float oa[2][3] = {};
    #pragma unroll
    for (int j = 0; j < 8; ++j) {
      float A = Ax[j], C = Cx[j];
      #pragma unroll
      for (int tt = 0; tt < 2; ++tt) {
        float fm = fmaf(A, bits2f((unsigned short)hrow[tt][0][j]), C);
        float fz = fmaf(A, bits2f((unsigned short)hrow[tt][1][j]), C);
        float fp = fmaf(A, bits2f((unsigned short)hrow[tt][2][j]), C);
        float d = fm*wod[j*3+0] + fz*wod[j*3+1] + fp*wod[j*3+2];
        d = d >= 0.f ? d : aodc*d;
        oa[tt][0] = fmaf(d, q0v[j], oa[tt][0]);
        oa[tt][1] = fmaf(d, q1v[j], oa[tt][1]);
        oa[tt][2] = fmaf(d, q2v[j], oa[tt][2]);
      }
    }
    #pragma unroll
    for (int st = 32; st > 0; st >>= 1) {
      #pragma unroll
      for (int tt = 0; tt < 2; ++tt) {
        oa[tt][0] += __shfl_xor(oa[tt][0], st);
        oa[tt][1] += __shfl_xor(oa[tt][1], st);
        oa[tt][2] += __shfl_xor(oa[tt][2], st);
      }
    }

    // ---- tap params (wave-uniform) -> LDS slots ----
    int S0[2][3], S1[2][3]; float G0[2][3], G1[2][3], GS[2][3];
    #pragma unroll
    for (int tt = 0; tt < 2; ++tt) {
      const float tf = (float)(t + tt);
      #pragma unroll
      for (int k = 0; k < 3; ++k) {
        float off = oa[tt][k];
        off = off >= 0.f ? off : aopc*off;
        float pos = tf + (float)(2*k) + off;
        pos = fminf(fmaxf(pos, tf), tf + 4.0f);
        int U = (int)floorf(pos);
        if (U > Tdim + 2) U = Tdim + 2;    // Lp-2
        float Uf = (float)U;
        G0[tt][k] = fmaxf(0.f, 1.f - fabsf(Uf - pos));
        G1[tt][k] = fmaxf(0.f, 1.f - fabsf(Uf + 1.f - pos));
        GS[tt][k] = G0[tt][k] + G1[tt][k];
        S0[tt][k] = U - t0;                // staged content = Hbuf[reflect(U-2)]
        S1[tt][k] = U - t0 + 1;            // staged content = Hbuf[reflect(U-1)]
      }
    }

    short8 s0v[2][3], s1v[2][3];
    #pragma unroll
    for (int tt = 0; tt < 2; ++tt)
      #pragma unroll
      for (int k = 0; k < 3; ++k) {
        s0v[tt][k] = *(const short8*)&tile[S0[tt][k]*512 + c8];
        s1v[tt][k] = *(const short8*)&tile[S1[tt][k]*512 + c8];
      }

    short8 yv[2];
    #pragma unroll
    for (int j = 0; j < 8; ++j) {
      float A = Ax[j], C = Cx[j];
      float w0 = wd[j*3+0], w1 = wd[j*3+1], w2 = wd[j*3+2];
      #pragma unroll
      for (int tt = 0; tt < 2; ++tt) {
        float ybase = fmaf(C, w0*GS[tt][0] + w1*GS[tt][1] + w2*GS[tt][2], bv[j]);
        float t0s = fmaf(G1[tt][0], bits2f((unsigned short)s1v[tt][0][j]), G0[tt][0]*bits2f((unsigned short)s0v[tt][0][j]));
        float t1s = fmaf(G1[tt][1], bits2f((unsigned short)s1v[tt][1][j]), G0[tt][1]*bits2f((unsigned short)s0v[tt][1][j]));
        float t2s = fmaf(G1[tt][2], bits2f((unsigned short)s1v[tt][2][j]), G0[tt][2]*bits2f((unsigned short)s0v[tt][2][j]));
        float acc2 = w0*t0s + w1*t1s + w2*t2s;
        float y = fmaf(A, acc2, ybase);
        float p = y >= 0.f ? y : a2*y;
        lsum += p; lss += p*p;
        yv[tt][j] = (short)f2bits(p);
      }
    }
    #pragma unroll
    for (int tt = 0; tt < 2; ++tt)
      *(short8*)&Ybuf[((size_t)m*Tdim + t + tt)*Hdim + c8] = yv[tt];
  }

  #pragma unroll
  for (int st = 32; st > 0; st >>= 1) {
    lsum += __shfl_xor(lsum, st);
    lss  += __shfl_xor(lss, st);
  }
  if (lane == 0) { rsum[w] = lsum; rss[w] = lss; }
  __syncthreads();
  if (tid == 0)
    part2[(size_t)m*63 + blockIdx.x] =
      make_float2(rsum[0]+rsum[1]+rsum[2]+rsum[3], rss[0]+rss[1]+rss[2]+rss[3]);
}

// ---------------- K3: reduce part2 + fold gLN2 into pointwise weights; emit W2 in FRAGMENT order
__global__ __launch_bounds__(64) void k_w2(
    const float2* __restrict__ part2,
    const float* __restrict__ g2w,
    const float* __restrict__ b2w,
    const float* __restrict__ pww,
    unsigned short* __restrict__ W2r,
    float* __restrict__ const2)
{
  const int bid = blockIdx.x;
  const int m = bid >> 7, b = bid & 127;
  const int tid = threadIdx.x;

  float s = 0.f, q = 0.f;
  if (tid < 63) { float2 p = part2[(size_t)m*63 + tid]; s = p.x; q = p.y; }
  #pragma unroll
  for (int st = 32; st > 0; st >>= 1) { s += __shfl_xor(s, st); q += __shfl_xor(q, st); }

  const float invn = 1.0f/(float)NPER;
  const float mean2 = s*invn;
  const float var2  = fmaxf(q*invn - mean2*mean2, 0.f);
  const float inv2  = 1.0f/sqrtf(var2 + EPSG);

  const int j8 = tid*8;
  float g2v[8], b2v[8], pv[8];
  #pragma unroll
  for (int j = 0; j < 8; j += 4) {
    *(float4*)&g2v[j] = *(const float4*)&g2w[j8 + j];
    *(float4*)&b2v[j] = *(const float4*)&b2w[j8 + j];
    *(float4*)&pv[j]  = *(const float4*)&pww[(size_t)b*Hdim + j8 + j];
  }
  float csum = 0.f;
  short8 wv8;
  #pragma unroll
  for (int j = 0; j < 8; ++j) {
    float A = g2v[j] * inv2;
    float C = b2v[j] - mean2*A;
    csum = fmaf(C, pv[j], csum);
    wv8[j] = (short)f2bits(A*pv[j]);
  }
  // fragment address: half=b>>6, nt=(b>>4)&3, l16=b&15; kc=tid>>4, ks=(tid>>2)&3, quad=tid&3
  {
    int half = b >> 6, nt = (b >> 4) & 3, l16 = b & 15;
    int kc = tid >> 4, ks = (tid >> 2) & 3, quad = tid & 3;
    int lane = quad*16 + l16;
    size_t f = ((((size_t)(m*2 + half)*4 + kc)*4 + ks)*4 + nt);
    *(short8*)&W2r[(f*64 + lane)*8] = wv8;
  }

  #pragma unroll
  for (int st = 32; st > 0; st >>= 1) csum += __shfl_down(csum, st);
  if (tid == 0) const2[m*Bdim + b] = csum;
}

// ---------------- K4: final GEMM Ybuf @ W2^T + const2 + residual -> out f32
// B-fragments direct from global (fragment-ordered, L2-resident); no LDS weight staging/barriers.
__global__ __launch_bounds__(256) void k_out(
    const unsigned short* __restrict__ Ybuf,
    const unsigned short* __restrict__ W2r,
    const float* __restrict__ const2,
    const float* __restrict__ x,
    float* __restrict__ out)
{
  __shared__ __align__(16) float ltf[64*68];
  const int tid = threadIdx.x;
  const int t0 = blockIdx.x*64;
  const int half = blockIdx.y;
  const int n0 = half*64;
  const int m  = blockIdx.z;
  const int lane = tid & 63, wv = tid >> 6, quad = lane >> 4, l16 = lane & 15;
  int tr = t0 + wv*16 + l16;
  int trc = tr < Tdim ? tr : Tdim-1;
  const unsigned short* arow = Ybuf + ((size_t)m*Tdim + trc)*Hdim;
  const short8* wf = (const short8*)W2r + (size_t)(m*2 + half)*64*64 + lane;

  floatx4 acc[4] = {};
  #pragma unroll
  for (int kc = 0; kc < 4; ++kc)
    #pragma unroll
    for (int ks = 0; ks < 4; ++ks) {
      short8 afr = *(const short8*)&arow[kc*128 + ks*32 + quad*8];
      #pragma unroll
      for (int nt = 0; nt < 4; ++nt)
        acc[nt] = __builtin_amdgcn_mfma_f32_16x16x32_bf16(
            afr, wf[((kc*4 + ks)*4 + nt)*64], acc[nt], 0, 0, 0);
    }

  #pragma unroll
  for (int nt = 0; nt < 4; ++nt) {
    int bl = nt*16 + l16;
    float cb = const2[m*Bdim + n0 + bl];
    #pragma unroll
    for (int r = 0; r < 4; ++r) {
      int tl = wv*16 + quad*4 + r;
      ltf[tl*68 + bl] = acc[nt][r] + cb;
    }
  }
  LDS_FENCE();   // wave-private transpose: write -> read
  {
    int tr2 = tid >> 2, ck = (tid & 3) * 16;
    int tg = t0 + tr2;
    if (tg < Tdim) {
      const float* xr = &x[((size_t)m*Tdim + tg)*Bdim + n0 + ck];
      float* orow = &out[((size_t)m*Tdim + tg)*Bdim + n0 + ck];
      #pragma unroll
      for (int j = 0; j < 4; ++j) {
        float4 v = *(const float4*)&ltf[tr2*68 + ck + j*4];
        float4 rx = *(const float4*)&xr[j*4];
        v.x += rx.x; v.y += rx.y; v.z += rx.z; v.w += rx.w;
        *(float4*)&orow[j*4] = v;
      }
    }
  }
}

extern "C" void kernel_launch(void* const* d_in, const int* in_sizes, int n_in,
                              void* d_out, int out_size, void* d_ws, size_t ws_size,
                              hipStream_t stream)
{
  (void)in_sizes; (void)n_in; (void)out_size; (void)ws_size;
  const float* x    = (const float*)d_in[0];
  const float* w1   = (const float*)d_in[1];
  const float* a1   = (const float*)d_in[2];
  const float* g1   = (const float*)d_in[3];
  const float* b1   = (const float*)d_in[4];
  const float* odw  = (const float*)d_in[5];
  const float* aodc = (const float*)d_in[6];
  const float* opw  = (const float*)d_in[7];
  const float* aopc = (const float*)d_in[8];
  const float* dww  = (const float*)d_in[9];
  const float* dwb  = (const float*)d_in[10];
  const float* a2   = (const float*)d_in[11];
  const float* g2   = (const float*)d_in[12];
  const float* b2   = (const float*)d_in[13];
  const float* pww  = (const float*)d_in[14];
  float* out = (float*)d_out;

  char* ws = (char*)d_ws;
  const size_t OFF_P1  = 0;          // part1 [M,63] float2: 4032 B
  const size_t OFF_C2  = 4096;       // const2 [M,B] f32: 4096 B
  const size_t OFF_P2  = 8192;       // part2 [M,63] float2: 4032 B
  const size_t OFF_W1R = 12288;      // w1r fragment bf16: 131072 B
  const size_t OFF_W2  = 143360;     // W2r [M,B,H] bf16 fragment order: 1048576 B
  const size_t OFF_H   = 1191936;    // Hbuf [M,T,H] bf16: 32768000 B
  const size_t OFF_Y   = 33959936;   // Ybuf [M,T,H] bf16: 32768000 B
  float2* part1  = (float2*)(ws + OFF_P1);
  float*  const2 = (float*)(ws + OFF_C2);
  float2* part2  = (float2*)(ws + OFF_P2);
  unsigned short* w1r  = (unsigned short*)(ws + OFF_W1R);
  unsigned short* W2r  = (unsigned short*)(ws + OFF_W2);
  unsigned short* Hbuf = (unsigned short*)(ws + OFF_H);
  unsigned short* Ybuf = (unsigned short*)(ws + OFF_Y);

  k_prep  <<<dim3(32), 256, 0, stream>>>(w1, w1r);
  k_conv1 <<<dim3(63, 8), 256, 0, stream>>>(x, w1r, a1, Hbuf, part1);
  k_deform<<<dim3(63, 8), 256, 0, stream>>>(Hbuf, part1, g1, b1, odw, aodc, opw, aopc, dww, dwb, a2, Ybuf, part2);
  k_w2    <<<dim3(1024), 64, 0, stream>>>(part2, g2, b2, pww, W2r, const2);
  k_out   <<<dim3(63, 2, 8), 256, 0, stream>>>(Ybuf, W2r, const2, x, out);
}